// Round 16
// baseline (95.335 us; speedup 1.0000x reference)
//
#include <hip/hip_runtime.h>
#include <hip/hip_bf16.h>

// DisenGCN forward — 2-dispatch, 16-blocks/side routing, gen-tagged sync,
// W1-projection hidden inside sweep sync gaps:
//   K1 (chip-wide): gather -> z0=proj(W0) -> znbA [bf16 norm, global] and
//                   z0raw [bf16, global, neighbors]. Bumps call_ctr.
//   K2 (32 blocks = 16/side x 1024 thr): per block: stage W1 in LDS.
//     sweeps 0..2 (znbA global): partial -> slot write (f24x2+gen16)
//       -> proj-W1 chunk (1/3 of my PRIVATE 256-row slice: z0raw -> LDS znbB)
//       -> poll 16 partials -> sum -> ego. (s==2: +row-0 proj(W1))
//     sweeps 3..5: route from LDS znbB (block-private!) -> slot -> poll -> ego.
//     finalize: block(0,0) polls all 32 s=5 partials, writes out.
//
// Key structural fact: block bg's route loop touches rows
// {bg*128 + t + m*2048 : t in [0,128), m in {0,1}} ONLY — its znbB slice is
// private, so it can live in LDS and be produced during the sync wait.
//
// Sync floor lesson (R12..R15): per-sweep exchange ~3.3 us regardless of
// protocol/payload — RTT+skew bound. So: hide work in it, and cut compute.
//
// ws: znbA[2*n_rows*64 bf16] | z0raw[same] | slots[6*2*SPB*32 u64] | call_ctr

#define EPS 1e-12f
#define LOG2E 1.44269504088896f
#define SPB 16             // blocks per side in K2
#define NBK (2 * SPB)

__device__ __forceinline__ float g16sum(float v) {
    v += __shfl_xor(v, 1, 64);
    v += __shfl_xor(v, 2, 64);
    v += __shfl_xor(v, 4, 64);
    v += __shfl_xor(v, 8, 64);
    return v;
}
__device__ __forceinline__ unsigned short f2bf(float f) {  // RNE
    unsigned int b = __float_as_uint(f);
    b += 0x7fffu + ((b >> 16) & 1u);
    return (unsigned short)(b >> 16);
}
__device__ __forceinline__ float bf2f(unsigned short u) {
    return __uint_as_float(((unsigned int)u) << 16);
}
__device__ __forceinline__ float bflo(unsigned int w) {
    return __uint_as_float(w << 16);
}
__device__ __forceinline__ float bfhi(unsigned int w) {
    return __uint_as_float(w & 0xffff0000u);
}

__device__ __forceinline__ unsigned long long pack2(float f0, float f1,
                                                    unsigned int gen16) {
    const unsigned long long a = __float_as_uint(f0) >> 8;   // top 24 bits
    const unsigned long long b = __float_as_uint(f1) >> 8;
    return (a << 40) | (b << 16) | (unsigned long long)gen16;
}
__device__ __forceinline__ float unpack0(unsigned long long v) {
    return __uint_as_float((unsigned int)(v >> 40) << 8);
}
__device__ __forceinline__ float unpack1(unsigned long long v) {
    return __uint_as_float(((unsigned int)(v >> 16) & 0xffffffu) << 8);
}
__device__ __forceinline__ unsigned long long slot_poll(unsigned long long* p,
                                                        unsigned int gen16) {
    unsigned long long v;
    for (;;) {
        v = atomicAdd(p, 0ull);                       // 64-bit RMW read
        if ((unsigned int)(v & 0xffffull) == gen16) break;
        __builtin_amdgcn_s_sleep(1);
    }
    return v;
}

// proj: lane chunk c=lane&15 holds input elems 4c..4c+3; output elem m in lane m.
__device__ __forceinline__ float proj_row4_g(const float xa[4],
                                             const float* __restrict__ W,
                                             const float* __restrict__ b, int lane) {
    const int k = lane >> 4, d = lane & 15;
    float sum = b[k * 16 + d];
    const float* __restrict__ Wp = W + k * 1024 + d;  // W[k][i][d]
#pragma unroll
    for (int i = 0; i < 64; ++i)
        sum = fmaf(__shfl(xa[i & 3], i >> 2, 64), Wp[i * 16], sum);
    return fmaxf(sum, 0.f);
}
// same but W staged in LDS i-major (sW[i*64+m])
__device__ __forceinline__ float proj_row4_l(const float xa[4],
                                             const float* __restrict__ sW,
                                             const float* __restrict__ b, int lane) {
    float sum = b[lane];
#pragma unroll
    for (int i = 0; i < 64; ++i)
        sum = fmaf(__shfl(xa[i & 3], i >> 2, 64), sW[i * 64 + lane], sum);
    return fmaxf(sum, 0.f);
}

// ---- K1: gather + proj L0 -> znbA + z0raw; bump call_ctr ----
__global__ __launch_bounds__(256) void k1_gather_proj(
    const int* __restrict__ user, const int* __restrict__ item,
    const int* __restrict__ nu, const int* __restrict__ ni,
    const float* __restrict__ Gu, const float* __restrict__ Gi,
    const float* __restrict__ W0, const float* __restrict__ b0,
    unsigned short* __restrict__ znbA, unsigned short* __restrict__ z0raw,
    unsigned int* __restrict__ call_ctr, int n_rows)
{
    if (blockIdx.x == 0 && threadIdx.x == 0) atomicAdd(call_ctr, 1u);

    const int lane = threadIdx.x & 63;
    const int wv   = threadIdx.x >> 6;
    const int rr   = blockIdx.x * 4 + wv;
    if (rr >= 2 * n_rows) return;
    const int side = rr >= n_rows;
    const int n    = rr - side * n_rows;
    const int c    = lane & 15;

    int idx; const float* G;
    if (n == 0) { idx = side ? item[0] : user[0];     G = side ? Gi : Gu; }
    else        { idx = side ? ni[n - 1] : nu[n - 1]; G = side ? Gu : Gi; }
    const float4 xv = ((const float4*)(G + (size_t)idx * 64))[c];
    const float xa[4] = {xv.x, xv.y, xv.z, xv.w};

    const float z0 = proj_row4_g(xa, W0, b0, lane);
    const float nrm0 = fmaxf(sqrtf(g16sum(z0 * z0)), EPS);
    znbA[(size_t)rr * 64 + lane] = f2bf(z0 / nrm0);
    if (n > 0) z0raw[(size_t)rr * 64 + lane] = f2bf(z0);   // neighbors only
}

// ---- K2: 6 sweeps (16 blocks/side) + hidden W1-proj + fused finalize ----
__global__ __launch_bounds__(1024) void k2_route_all(
    const unsigned short* __restrict__ znbA, const unsigned short* __restrict__ z0raw,
    const float* __restrict__ W1, const float* __restrict__ b1,
    unsigned long long* __restrict__ slots,
    const unsigned int* __restrict__ call_ctr,
    float* __restrict__ out, int n_neigh)
{
    const int n_rows = n_neigh + 1;
    const int tid  = threadIdx.x;
    const int lane = tid & 63;
    const int wv   = tid >> 6;
    const int side = blockIdx.x & 1;
    const int bg   = blockIdx.x >> 1;
    const unsigned short* __restrict__ zA  = znbA  + (size_t)side * n_rows * 64;
    const unsigned short* __restrict__ z0r = z0raw + (size_t)side * n_rows * 64;
    const unsigned int genbase = (*call_ctr) * 8u;   // dispatch-boundary read

    __shared__ float sW[4096];            // W1 i-major: sW[i*64 + m]
    __shared__ float red[16][64];
    __shared__ float sEgo[64];
    __shared__ float sTmp[64];
    __shared__ unsigned short zB[256 * 64];  // my private znbB slice (rows L)

    for (int q = tid; q < 4096; q += 1024) {
        const int i = q >> 6, m = q & 63;
        sW[q] = W1[(m >> 4) * 1024 + i * 16 + (m & 15)];
    }
    if (tid < 64) sEgo[tid] = bf2f(zA[tid]) * LOG2E;  // normalized row 0
    __syncthreads();

    const int j   = lane & 7;
    const int g   = tid >> 3;                // row-group within block [0,128)

    for (int s = 0; s < 6; ++s) {
        const unsigned int gen = (genbase + (unsigned int)s + 1u) & 0xffffu;
        float ego[8];
#pragma unroll
        for (int m = 0; m < 8; ++m) ego[m] = sEgo[j * 8 + m];

        float a8[8] = {0.f, 0.f, 0.f, 0.f, 0.f, 0.f, 0.f, 0.f};
#pragma unroll
        for (int m = 0; m < 2; ++m) {
            const int r = bg * 128 + g + m * (SPB * 128);  // my neighbor row id
            if (r >= n_neigh) break;
            uint4 q;
            if (s < 3) q = *(const uint4*)(zA + (((size_t)r + 1) << 6) + (j << 3));
            else       q = *(const uint4*)(zB + ((m * 128 + g) << 6) + (j << 3));
            float x[8];
            x[0] = bflo(q.x); x[1] = bfhi(q.x);
            x[2] = bflo(q.y); x[3] = bfhi(q.y);
            x[4] = bflo(q.z); x[5] = bfhi(q.z);
            x[6] = bflo(q.w); x[7] = bfhi(q.w);
            float partial = 0.f;
#pragma unroll
            for (int mm = 0; mm < 8; ++mm) partial = fmaf(x[mm], ego[mm], partial);
            const float dp = partial + __shfl_xor(partial, 1, 64);
            const float eo = exp2f(dp);
            float den = eo + __shfl_xor(eo, 2, 64);
            den += __shfl_xor(den, 4, 64);
            const float p = eo * __builtin_amdgcn_rcpf(den);
#pragma unroll
            for (int mm = 0; mm < 8; ++mm) a8[mm] = fmaf(p, x[mm], a8[mm]);
        }
#pragma unroll
        for (int mask = 8; mask <= 32; mask <<= 1)
#pragma unroll
            for (int m = 0; m < 8; ++m) a8[m] += __shfl_xor(a8[m], mask, 64);
        if (lane < 8) {
#pragma unroll
            for (int m = 0; m < 8; ++m) red[wv][lane * 8 + m] = a8[m];
        }
        __syncthreads();                                  // (1) red complete

        unsigned long long* slotbase = slots + (size_t)(s * 2 + side) * SPB * 32;
        if (wv == 0) {
            float ssum = 0.f;
#pragma unroll
            for (int w = 0; w < 16; ++w) ssum += red[w][lane];
            const float f0 = __shfl(ssum, (lane & 31) * 2, 64);
            const float f1 = __shfl(ssum, (lane & 31) * 2 + 1, 64);
            if (lane < 32)
                atomicExch(&slotbase[bg * 32 + lane], pack2(f0, f1, gen));
        }
        __syncthreads();                                  // (2) red reusable

        // ---- hidden work: proj-W1 chunk s (sweeps 0..2 only) ----
        if (s < 3) {
            const int lo = s * 86, hi = (s == 2) ? 256 : (s + 1) * 86;
            for (int L = lo + wv; L < hi; L += 16) {
                const int r = bg * 128 + (L & 127) + (L >> 7) * (SPB * 128);
                if (r >= n_neigh) continue;
                const int c = lane & 15;
                const ushort4 uv = ((const ushort4*)(z0r + (((size_t)r + 1) << 6)))[c];
                const float xa[4] = {bf2f(uv.x), bf2f(uv.y), bf2f(uv.z), bf2f(uv.w)};
                const float z1 = proj_row4_l(xa, sW, b1, lane);
                const float nrm = fmaxf(sqrtf(g16sum(z1 * z1)), EPS);
                zB[(L << 6) + lane] = f2bf(z1 / nrm);
            }
        }

        if (s < 5) {
            if (wv < 8) {                    // wave w: partials 2w, 2w+1
                const int p = 2 * wv + (lane >> 5);
                const int e = lane & 31;
                const unsigned long long v = slot_poll(&slotbase[p * 32 + e], gen);
                ((float2*)red[p])[e] = make_float2(unpack0(v), unpack1(v));
            }
            __syncthreads();                              // (3) partials in LDS
            if (wv == 0) {
                float e = 0.f;
#pragma unroll
                for (int bb = 0; bb < SPB; ++bb) e += red[bb][lane];
                if (s == 2) sTmp[lane] = e;               // raw routed L0
                else sEgo[lane] = (e / fmaxf(sqrtf(g16sum(e * e)), EPS)) * LOG2E;
            }
            __syncthreads();                              // (4)
            if (s == 2) {
                if (wv == 0) {                            // row-0 proj(W1)
                    float xa[4];
#pragma unroll
                    for (int jj = 0; jj < 4; ++jj) xa[jj] = sTmp[((lane & 15) << 2) | jj];
                    const float sum = proj_row4_l(xa, sW, b1, lane);
                    sEgo[lane] = (sum / fmaxf(sqrtf(g16sum(sum * sum)), EPS)) * LOG2E;
                }
                __syncthreads();                          // (5)
            }
        } else if (side == 0 && bg == 0) {
            // finalize: 16 waves read 32 partials (pair-summed in-wave)
            const int P  = 2 * wv + (lane >> 5);          // [0,32)
            const int s2 = P >> 4, bb = P & 15;
            const int e  = lane & 31;
            unsigned long long* sb2 = slots + (size_t)(5 * 2 + s2) * SPB * 32;
            const unsigned long long v = slot_poll(&sb2[bb * 32 + e], gen);
            float f0 = unpack0(v), f1 = unpack1(v);
            f0 += __shfl_xor(f0, 32, 64);                 // P and P^1 summed
            f1 += __shfl_xor(f1, 32, 64);
            if (lane < 32) ((float2*)red[wv])[e] = make_float2(f0, f1);
            __syncthreads();
            if (wv == 0) {
                float u = 0.f, v2 = 0.f;
#pragma unroll
                for (int w = 0; w < 8; ++w)  u  += red[w][lane];
#pragma unroll
                for (int w = 8; w < 16; ++w) v2 += red[w][lane];
                out[1 + lane]  = u;
                out[65 + lane] = v2;
                float p = u * v2;
#pragma unroll
                for (int sh = 32; sh >= 1; sh >>= 1) p += __shfl_xor(p, sh, 64);
                if (lane == 0) out[0] = p;
            }
        }
    }
}

extern "C" void kernel_launch(void* const* d_in, const int* in_sizes, int n_in,
                              void* d_out, int out_size, void* d_ws, size_t ws_size,
                              hipStream_t stream) {
    const int*   user       = (const int*)d_in[0];
    const int*   item       = (const int*)d_in[1];
    const int*   neigh_user = (const int*)d_in[2];
    const int*   neigh_item = (const int*)d_in[3];
    const float* Gu         = (const float*)d_in[4];
    const float* Gi         = (const float*)d_in[5];
    const float* W0         = (const float*)d_in[6];
    const float* b0         = (const float*)d_in[7];
    const float* W1         = (const float*)d_in[8];
    const float* b1         = (const float*)d_in[9];
    float* out = (float*)d_out;

    const int n_neigh = in_sizes[2];
    const int n_rows  = n_neigh + 1;
    const size_t rowsz = (size_t)2 * n_rows * 64;

    unsigned short*     znbA  = (unsigned short*)d_ws;
    unsigned short*     z0raw = znbA + rowsz;
    unsigned long long* slots = (unsigned long long*)(z0raw + rowsz);
    unsigned int*       ctr   = (unsigned int*)(slots + 6 * 2 * SPB * 32);

    hipLaunchKernelGGL(k1_gather_proj, dim3((2 * n_rows + 3) / 4), dim3(256), 0, stream,
                       user, item, neigh_user, neigh_item, Gu, Gi, W0, b0,
                       znbA, z0raw, ctr, n_rows);
    hipLaunchKernelGGL(k2_route_all, dim3(NBK), dim3(1024), 0, stream,
                       znbA, z0raw, W1, b1, slots, ctr, out, n_neigh);
}